// Round 8
// baseline (108.094 us; speedup 1.0000x reference)
//
#include <hip/hip_runtime.h>
#include <math.h>

#define BB 32
#define TT 1024
#define HH 128

typedef __attribute__((ext_vector_type(8))) short short8;
typedef __attribute__((ext_vector_type(4))) float floatx4;

__device__ __forceinline__ unsigned short f2bf(float f) {
    unsigned u = __float_as_uint(f);
    u += 0x7fffu + ((u >> 16) & 1u);
    return (unsigned short)(u >> 16);
}

// Kernel A: gather embedding rows, normalize (store bf16), compute lambda.
__global__ __launch_bounds__(256)
void gather_norm(const int* __restrict__ seq,
                 const float* __restrict__ embd,
                 const float* __restrict__ lam_w,
                 const float* __restrict__ lam_b,
                 unsigned short* __restrict__ xbf,
                 float* __restrict__ lam) {
    const int lane = threadIdx.x & 63;
    const int half = lane >> 5;
    const int l32  = lane & 31;
    const int row  = blockIdx.x * 8 + (threadIdx.x >> 6) * 2 + half;
    const int idx  = seq[row];
    float4 v = ((const float4*)(embd + (size_t)idx * HH))[l32];
    float4 w = ((const float4*)lam_w)[l32];
    float ss = v.x * v.x + v.y * v.y + v.z * v.z + v.w * v.w;
    float dw = v.x * w.x + v.y * w.y + v.z * w.z + v.w * w.w;
    #pragma unroll
    for (int off = 16; off > 0; off >>= 1) {
        ss += __shfl_xor(ss, off);
        dw += __shfl_xor(dw, off);
    }
    float inv = 1.0f / sqrtf(ss);
    unsigned b0 = f2bf(v.x * inv), b1 = f2bf(v.y * inv);
    unsigned b2 = f2bf(v.z * inv), b3 = f2bf(v.w * inv);
    uint2 o; o.x = b0 | (b1 << 16); o.y = b2 | (b3 << 16);
    ((uint2*)(xbf + (size_t)row * HH))[l32] = o;
    if (l32 == 0) lam[row] = expf(dw + lam_b[0]);
}

// local partials for one (tile, t-group): no cross-lane ops.
__device__ __forceinline__ void tile_part(const floatx4& acc, int s0, int t,
                                          float lmt, const float4& yv,
                                          float& S, float& W, float& Y) {
    float v0 = (s0 + 0 < t) ? (acc[0] + 1.f) * 0.5f : 0.f;
    float v1 = (s0 + 1 < t) ? (acc[1] + 1.f) * 0.5f : 0.f;
    float v2 = (s0 + 2 < t) ? (acc[2] + 1.f) * 0.5f : 0.f;
    float v3 = (s0 + 3 < t) ? (acc[3] + 1.f) * 0.5f : 0.f;
    float suf3 = v3;
    float suf2 = v2 + suf3;
    float suf1 = v1 + suf2;
    float suf0 = v0 + suf1;
    float e0 = __expf(-lmt * suf0);
    float e1 = __expf(-lmt * suf1);
    float e2 = __expf(-lmt * suf2);
    float e3 = __expf(-lmt * suf3);
    float w0 = v0 * e0, w1 = v1 * e1, w2 = v2 * e2, w3 = v3 * e3;
    S = suf0;
    W = (w0 + w1) + (w2 + w3);
    Y = (w0 * yv.x + w1 * yv.y) + (w2 * yv.z + w3 * yv.w);
}

// cross-quad resolution: apply deferred decay, update running total.
__device__ __forceinline__ void resolve(float S, float W, float Y, float lmt,
                                        int tl, int quad,
                                        float& above, float& wl, float& yl) {
    float q0 = __shfl(S, tl);
    float q1 = __shfl(S, tl + 16);
    float q2 = __shfl(S, tl + 32);
    float q3 = __shfl(S, tl + 48);
    float tT = (q0 + q1) + (q2 + q3);
    float hq = (quad < 1 ? q1 : 0.f) + (quad < 2 ? q2 : 0.f) +
               (quad < 3 ? q3 : 0.f);
    float sc = __expf(-lmt * (above + hq));
    wl += W * sc;
    yl += Y * sc;
    above += tT;
}

// issue the loads for sub-batch sb into (a[8], yA, yB). Indices clamped so
// out-of-range prefetches stay in-bounds (results masked at compute time).
__device__ __forceinline__ void issue_loads(const unsigned short* __restrict__ xbf,
                                            const float* __restrict__ yb,
                                            size_t rowbase, int tl, int quad,
                                            int start, int cnt, int sb,
                                            short8 a[8], float4& yA, float4& yB) {
    int jA = start + 2 * sb;
    if (jA < 0) jA = 0;
    const bool vB = (2 * sb + 1) < cnt && sb >= 0;
    const int sbaseA = jA << 4;
    const int sbaseB = vB ? ((jA + 1) << 4) : sbaseA;
    const short8* arA = (const short8*)(xbf + (rowbase + sbaseA + tl) * HH);
    const short8* arB = (const short8*)(xbf + (rowbase + sbaseB + tl) * HH);
    #pragma unroll
    for (int kk = 0; kk < 4; kk++) {
        a[kk]     = arA[kk * 4 + quad];
        a[4 + kk] = arB[kk * 4 + quad];
    }
    yA = ((const float4*)(yb + sbaseA))[quad];
    yB = ((const float4*)(yb + sbaseB))[quad];
}

// compute one sub-batch from a prefetched buffer.
__device__ __forceinline__ void compute_sb(int sb, int start, int cnt,
                                           const short8 a[8],
                                           const short8 bq0[4], const short8 bq1[4],
                                           const float4& yA, const float4& yB,
                                           int t0, int t1, float lam0, float lam1,
                                           int tl, int quad,
                                           float& above0, float& wl0, float& yl0,
                                           float& above1, float& wl1, float& yl1) {
    const bool vA = (2 * sb)     < cnt && sb >= 0;
    const bool vB = (2 * sb + 1) < cnt && sb >= 0;
    const int jA = start + 2 * sb;
    floatx4 aA0 = {0,0,0,0}, aA1 = {0,0,0,0};
    floatx4 aB0 = {0,0,0,0}, aB1 = {0,0,0,0};
    #pragma unroll
    for (int kk = 0; kk < 4; kk++) {
        aA0 = __builtin_amdgcn_mfma_f32_16x16x32_bf16(a[kk],     bq0[kk], aA0, 0, 0, 0);
        aA1 = __builtin_amdgcn_mfma_f32_16x16x32_bf16(a[kk],     bq1[kk], aA1, 0, 0, 0);
        aB0 = __builtin_amdgcn_mfma_f32_16x16x32_bf16(a[4 + kk], bq0[kk], aB0, 0, 0, 0);
        aB1 = __builtin_amdgcn_mfma_f32_16x16x32_bf16(a[4 + kk], bq1[kk], aB1, 0, 0, 0);
    }
    const int s0A = vA ? ((jA << 4) + quad * 4)       : 0x40000000;
    const int s0B = vB ? (((jA + 1) << 4) + quad * 4) : 0x40000000;

    float SB0, WB0, YB0, SB1, WB1, YB1;
    float SA0, WA0, YA0, SA1, WA1, YA1;
    tile_part(aB0, s0B, t0, lam0, yB, SB0, WB0, YB0);
    tile_part(aB1, s0B, t1, lam1, yB, SB1, WB1, YB1);
    tile_part(aA0, s0A, t0, lam0, yA, SA0, WA0, YA0);
    tile_part(aA1, s0A, t1, lam1, yA, SA1, WA1, YA1);

    resolve(SB0, WB0, YB0, lam0, tl, quad, above0, wl0, yl0);
    resolve(SB1, WB1, YB1, lam1, tl, quad, above1, wl1, yl1);
    resolve(SA0, WA0, YA0, lam0, tl, quad, above0, wl0, yl0);
    resolve(SA1, WA1, YA1, lam1, tl, quad, above1, wl1, yl1);
}

// Kernel B: one block per (b, u = 32-t supertile); 4 waves split the s-range;
// t-pairing (each A-tile feeds 8 MFMAs); explicit double-buffered register
// prefetch so sub-batch N-1's loads fly while sub-batch N computes.
__global__ __launch_bounds__(256, 3)
void sim_fused(const unsigned short* __restrict__ xbf,
               const float* __restrict__ lam,
               const float* __restrict__ y,
               float* __restrict__ out) {
    const int b    = blockIdx.x & 31;
    const int u    = 31 - (blockIdx.x >> 5);     // largest supertiles first
    const int tid  = threadIdx.x;
    const int w    = tid >> 6;
    const int lane = tid & 63;
    const int tl   = lane & 15;
    const int quad = lane >> 4;

    const size_t rowbase = (size_t)b * TT;
    const int t0 = u * 32 + tl;
    const int t1 = t0 + 16;
    const float lam0 = lam[rowbase + t0];
    const float lam1 = lam[rowbase + t1];
    const float* yb = y + rowbase;

    __shared__ float Wc[4][2][16], Yc[4][2][16], Tc[4][2][16];

    // preload both B-fragment sets (t-tile 2u and 2u+1)
    short8 bq0[4], bq1[4];
    const short8* q0r = (const short8*)(xbf + (rowbase + t0) * HH);
    const short8* q1r = (const short8*)(xbf + (rowbase + t1) * HH);
    #pragma unroll
    for (int kk = 0; kk < 4; kk++) {
        bq0[kk] = q0r[kk * 4 + quad];
        bq1[kk] = q1r[kk * 4 + quad];
    }

    // wave's contiguous range of 16-wide s-tiles
    const int nst = 2 * u + 2;
    const int qn = nst >> 2, rem = nst & 3;
    const int cnt   = qn + (w < rem ? 1 : 0);
    const int start = w * qn + (w < rem ? w : rem);

    float wl0 = 0.f, yl0 = 0.f, above0 = 0.f;
    float wl1 = 0.f, yl1 = 0.f, above1 = 0.f;

    const int nsb = (cnt + 1) >> 1;

    short8 abuf0[8], abuf1[8];
    float4 y0A, y0B, y1A, y1B;

    int sb = nsb - 1;
    issue_loads(xbf, yb, rowbase, tl, quad, start, cnt, sb, abuf0, y0A, y0B);
    for (; sb >= 0; sb -= 2) {
        issue_loads(xbf, yb, rowbase, tl, quad, start, cnt, sb - 1,
                    abuf1, y1A, y1B);
        compute_sb(sb, start, cnt, abuf0, bq0, bq1, y0A, y0B,
                   t0, t1, lam0, lam1, tl, quad,
                   above0, wl0, yl0, above1, wl1, yl1);
        issue_loads(xbf, yb, rowbase, tl, quad, start, cnt, sb - 2,
                    abuf0, y0A, y0B);
        compute_sb(sb - 1, start, cnt, abuf1, bq0, bq1, y1A, y1B,
                   t0, t1, lam0, lam1, tl, quad,
                   above0, wl0, yl0, above1, wl1, yl1);
    }

    // ---- cross-quad final reduce, wave partials to LDS ----
    float Wt0 = __shfl(wl0, tl) + __shfl(wl0, tl + 16) +
                __shfl(wl0, tl + 32) + __shfl(wl0, tl + 48);
    float Yt0 = __shfl(yl0, tl) + __shfl(yl0, tl + 16) +
                __shfl(yl0, tl + 32) + __shfl(yl0, tl + 48);
    float Wt1 = __shfl(wl1, tl) + __shfl(wl1, tl + 16) +
                __shfl(wl1, tl + 32) + __shfl(wl1, tl + 48);
    float Yt1 = __shfl(yl1, tl) + __shfl(yl1, tl + 16) +
                __shfl(yl1, tl + 32) + __shfl(yl1, tl + 48);
    if (quad == 0) {
        Wc[w][0][tl] = Wt0; Yc[w][0][tl] = Yt0; Tc[w][0][tl] = above0;
        Wc[w][1][tl] = Wt1; Yc[w][1][tl] = Yt1; Tc[w][1][tl] = above1;
    }
    __syncthreads();

    // ---- merge 4 wave-chunks (wave 3 = highest s, no rescale) ----
    if (tid < 32) {
        const int g = tid >> 4, l = tid & 15;
        const int t = u * 32 + g * 16 + l;
        const float lt = lam[rowbase + t];
        float A = 0.f, W = 0.f, Y = 0.f;
        #pragma unroll
        for (int ww = 3; ww >= 0; --ww) {
            float sc = __expf(-lt * A);
            W += Wc[ww][g][l] * sc;
            Y += Yc[ww][g][l] * sc;
            A += Tc[ww][g][l];
        }
        float r = Y / (W + 1e-6f);
        out[rowbase + t] = fminf(fmaxf(r, 0.01f), 0.99f);
    }
}

extern "C" void kernel_launch(void* const* d_in, const int* in_sizes, int n_in,
                              void* d_out, int out_size, void* d_ws, size_t ws_size,
                              hipStream_t stream) {
    const float* y     = (const float*)d_in[0];
    const int*   seq   = (const int*)  d_in[1];
    const float* embd  = (const float*)d_in[2];
    const float* lam_w = (const float*)d_in[3];
    const float* lam_b = (const float*)d_in[4];
    float* out = (float*)d_out;

    unsigned short* xbf = (unsigned short*)d_ws;            // 8 MB
    float* lam = (float*)(xbf + (size_t)BB * TT * HH);      // 128 KB

    gather_norm<<<BB * TT / 8, 256, 0, stream>>>(seq, embd, lam_w, lam_b, xbf, lam);
    sim_fused<<<BB * 32, 256, 0, stream>>>(xbf, lam, y, out);
}

// Round 9
// 107.438 us; speedup vs baseline: 1.0061x; 1.0061x over previous
//
#include <hip/hip_runtime.h>
#include <math.h>

#define BB 32
#define TT 1024
#define HH 128

typedef __attribute__((ext_vector_type(8))) short short8;
typedef __attribute__((ext_vector_type(16))) float floatx16;

__device__ __forceinline__ unsigned short f2bf(float f) {
    unsigned u = __float_as_uint(f);
    u += 0x7fffu + ((u >> 16) & 1u);
    return (unsigned short)(u >> 16);
}

// Kernel A: gather embedding rows, normalize (store bf16), compute lambda.
__global__ __launch_bounds__(256)
void gather_norm(const int* __restrict__ seq,
                 const float* __restrict__ embd,
                 const float* __restrict__ lam_w,
                 const float* __restrict__ lam_b,
                 unsigned short* __restrict__ xbf,
                 float* __restrict__ lam) {
    const int lane = threadIdx.x & 63;
    const int half = lane >> 5;
    const int l32  = lane & 31;
    const int row  = blockIdx.x * 8 + (threadIdx.x >> 6) * 2 + half;
    const int idx  = seq[row];
    float4 v = ((const float4*)(embd + (size_t)idx * HH))[l32];
    float4 w = ((const float4*)lam_w)[l32];
    float ss = v.x * v.x + v.y * v.y + v.z * v.z + v.w * v.w;
    float dw = v.x * w.x + v.y * w.y + v.z * w.z + v.w * w.w;
    #pragma unroll
    for (int off = 16; off > 0; off >>= 1) {
        ss += __shfl_xor(ss, off);
        dw += __shfl_xor(dw, off);
    }
    float inv = 1.0f / sqrtf(ss);
    unsigned b0 = f2bf(v.x * inv), b1 = f2bf(v.y * inv);
    unsigned b2 = f2bf(v.z * inv), b3 = f2bf(v.w * inv);
    uint2 o; o.x = b0 | (b1 << 16); o.y = b2 | (b3 << 16);
    ((uint2*)(xbf + (size_t)row * HH))[l32] = o;
    if (l32 == 0) lam[row] = expf(dw + lam_b[0]);
}

// Kernel B: one block per (b, tt = 32-wide t-tile). 4 waves split the s-range
// [0, 32*(tt+1)) into contiguous 32-wide s-tiles (wave 3 = highest s).
// Per tile: D = Xs * Xq^T via v_mfma_f32_32x32x16_bf16 (8 K-steps).
// C/D layout: col = lane&31 (t), row = (reg&3) + 8*(reg>>2) + 4*(lane>>5)
//  -> each lane holds 4 GROUPS of 4 consecutive s-rows; group G = 2g + h
//     (h = lane>>5) covers s = s_base + 4G .. +3.
// Scan: in-lane suffix within each group + ONE shfl_xor(32) per group total
// to see the other half's groups; pair-suffix gives deferred decay factors.
// exp(-lam*(sufin + D)) == exp(-lam*sufin) * exp(-lam*D) keeps the hot path
// shuffle-light. Wave chunks merged in LDS via the associative rescale.
__global__ __launch_bounds__(256, 3)
void sim_fused(const unsigned short* __restrict__ xbf,
               const float* __restrict__ lam,
               const float* __restrict__ y,
               float* __restrict__ out) {
    const int b    = blockIdx.x & 31;
    const int tt   = 31 - (blockIdx.x >> 5);     // largest t-tiles first
    const int tid  = threadIdx.x;
    const int w    = tid >> 6;
    const int lane = tid & 63;
    const int col  = lane & 31;
    const int h    = lane >> 5;

    const int t_base = tt * 32;
    const int t      = t_base + col;
    const size_t rowbase = (size_t)b * TT;
    const float lam_t = lam[rowbase + t];
    const float* yb = y + rowbase;

    __shared__ float Wc[4][32], Yc[4][32], Tc[4][32];

    // preload B fragments (Xq rows): frag kk = row[k=16kk + 8h .. +8]
    short8 bq[8];
    const short8* qrow = (const short8*)(xbf + (rowbase + t) * HH);
    #pragma unroll
    for (int kk = 0; kk < 8; kk++) bq[kk] = qrow[kk * 2 + h];

    // wave's contiguous range of 32-wide s-tiles
    const int nst = tt + 1;
    const int qn = nst >> 2, rem = nst & 3;
    const int cnt   = qn + (w < rem ? 1 : 0);
    const int start = w * qn + (w < rem ? w : rem);

    float wl = 0.f, yl = 0.f, run = 0.f;

    for (int i = cnt - 1; i >= 0; --i) {
        const int stile  = start + i;
        const int s_base = stile << 5;

        // ---- loads for this tile (A fragments + y) ----
        const short8* ar = (const short8*)(xbf + (rowbase + s_base + col) * HH);
        short8 af[8];
        #pragma unroll
        for (int kk = 0; kk < 8; kk++) af[kk] = ar[kk * 2 + h];
        float4 yv[4];
        #pragma unroll
        for (int g = 0; g < 4; g++)
            yv[g] = *(const float4*)(yb + s_base + 8 * g + 4 * h);

        // ---- 8 MFMAs ----
        floatx16 acc = {0,0,0,0,0,0,0,0,0,0,0,0,0,0,0,0};
        #pragma unroll
        for (int kk = 0; kk < 8; kk++)
            acc = __builtin_amdgcn_mfma_f32_32x32x16_bf16(af[kk], bq[kk], acc, 0, 0, 0);

        // ---- per-group local partials (no cross-lane) ----
        const bool domask = (stile == tt);   // wave-uniform
        float S[4], Wg[4], Yg[4];
        #pragma unroll
        for (int g = 0; g < 4; g++) {
            float v0 = (acc[4*g + 0] + 1.f) * 0.5f;
            float v1 = (acc[4*g + 1] + 1.f) * 0.5f;
            float v2 = (acc[4*g + 2] + 1.f) * 0.5f;
            float v3 = (acc[4*g + 3] + 1.f) * 0.5f;
            if (domask) {
                const int sg = s_base + 8 * g + 4 * h;
                v0 = (sg + 0 < t) ? v0 : 0.f;
                v1 = (sg + 1 < t) ? v1 : 0.f;
                v2 = (sg + 2 < t) ? v2 : 0.f;
                v3 = (sg + 3 < t) ? v3 : 0.f;
            }
            float suf3 = v3;
            float suf2 = v2 + suf3;
            float suf1 = v1 + suf2;
            float suf0 = v0 + suf1;
            float e0 = __expf(-lam_t * suf0);
            float e1 = __expf(-lam_t * suf1);
            float e2 = __expf(-lam_t * suf2);
            float e3 = __expf(-lam_t * suf3);
            float w0 = v0 * e0, w1 = v1 * e1, w2 = v2 * e2, w3 = v3 * e3;
            S[g]  = suf0;
            Wg[g] = (w0 + w1) + (w2 + w3);
            Yg[g] = (w0 * yv[g].x + w1 * yv[g].y) +
                    (w2 * yv[g].z + w3 * yv[g].w);
        }

        // ---- cross-half exchange of group totals (4 shuffles) ----
        float O0 = __shfl_xor(S[0], 32);
        float O1 = __shfl_xor(S[1], 32);
        float O2 = __shfl_xor(S[2], 32);
        float O3 = __shfl_xor(S[3], 32);
        float P0 = S[0] + O0, P1 = S[1] + O1, P2 = S[2] + O2, P3 = S[3] + O3;
        float Q3 = 0.f;
        float Q2 = P3;
        float Q1 = P2 + P3;
        float Q0 = P1 + Q1;
        // group 2g (h==0) additionally decays through group 2g+1 (= O_g)
        float a0 = Q0 + (h ? 0.f : O0);
        float a1 = Q1 + (h ? 0.f : O1);
        float a2 = Q2 + (h ? 0.f : O2);
        float a3 = Q3 + (h ? 0.f : O3);
        float sc0 = __expf(-lam_t * (run + a0));
        float sc1 = __expf(-lam_t * (run + a1));
        float sc2 = __expf(-lam_t * (run + a2));
        float sc3 = __expf(-lam_t * (run + a3));
        wl += (Wg[0] * sc0 + Wg[1] * sc1) + (Wg[2] * sc2 + Wg[3] * sc3);
        yl += (Yg[0] * sc0 + Yg[1] * sc1) + (Yg[2] * sc2 + Yg[3] * sc3);
        run += P0 + Q0;
    }

    // ---- cross-half final reduce, wave partials to LDS ----
    float Wt = wl + __shfl_xor(wl, 32);
    float Yt = yl + __shfl_xor(yl, 32);
    if (lane < 32) {
        Wc[w][col] = Wt;
        Yc[w][col] = Yt;
        Tc[w][col] = run;    // identical across halves by construction
    }
    __syncthreads();

    // ---- merge 4 wave-chunks (wave 3 = highest s, no rescale) ----
    if (tid < 32) {
        const int tm = t_base + tid;
        const float lt = lam[rowbase + tm];
        float A = 0.f, W = 0.f, Y = 0.f;
        #pragma unroll
        for (int ww = 3; ww >= 0; --ww) {
            float sc = __expf(-lt * A);
            W += Wc[ww][tid] * sc;
            Y += Yc[ww][tid] * sc;
            A += Tc[ww][tid];
        }
        float r = Y / (W + 1e-6f);
        out[rowbase + tm] = fminf(fmaxf(r, 0.01f), 0.99f);
    }
}

extern "C" void kernel_launch(void* const* d_in, const int* in_sizes, int n_in,
                              void* d_out, int out_size, void* d_ws, size_t ws_size,
                              hipStream_t stream) {
    const float* y     = (const float*)d_in[0];
    const int*   seq   = (const int*)  d_in[1];
    const float* embd  = (const float*)d_in[2];
    const float* lam_w = (const float*)d_in[3];
    const float* lam_b = (const float*)d_in[4];
    float* out = (float*)d_out;

    unsigned short* xbf = (unsigned short*)d_ws;            // 8 MB
    float* lam = (float*)(xbf + (size_t)BB * TT * HH);      // 128 KB

    gather_norm<<<BB * TT / 8, 256, 0, stream>>>(seq, embd, lam_w, lam_b, xbf, lam);
    sim_fused<<<BB * 32, 256, 0, stream>>>(xbf, lam, y, out);
}

// Round 10
// 107.028 us; speedup vs baseline: 1.0100x; 1.0038x over previous
//
#include <hip/hip_runtime.h>
#include <math.h>

#define BB 32
#define TT 1024
#define HH 128
#define LOG2E 1.4426950408889634f

typedef __attribute__((ext_vector_type(8))) short short8;
typedef __attribute__((ext_vector_type(4))) float floatx4;

__device__ __forceinline__ unsigned short f2bf(float f) {
    unsigned u = __float_as_uint(f);
    u += 0x7fffu + ((u >> 16) & 1u);
    return (unsigned short)(u >> 16);
}

// Kernel A: gather embedding rows, normalize (store bf16), compute lambda.
__global__ __launch_bounds__(256)
void gather_norm(const int* __restrict__ seq,
                 const float* __restrict__ embd,
                 const float* __restrict__ lam_w,
                 const float* __restrict__ lam_b,
                 unsigned short* __restrict__ xbf,
                 float* __restrict__ lam) {
    const int lane = threadIdx.x & 63;
    const int half = lane >> 5;
    const int l32  = lane & 31;
    const int row  = blockIdx.x * 8 + (threadIdx.x >> 6) * 2 + half;
    const int idx  = seq[row];
    float4 v = ((const float4*)(embd + (size_t)idx * HH))[l32];
    float4 w = ((const float4*)lam_w)[l32];
    float ss = v.x * v.x + v.y * v.y + v.z * v.z + v.w * v.w;
    float dw = v.x * w.x + v.y * w.y + v.z * w.z + v.w * w.w;
    #pragma unroll
    for (int off = 16; off > 0; off >>= 1) {
        ss += __shfl_xor(ss, off);
        dw += __shfl_xor(dw, off);
    }
    float inv = 1.0f / sqrtf(ss);
    unsigned b0 = f2bf(v.x * inv), b1 = f2bf(v.y * inv);
    unsigned b2 = f2bf(v.z * inv), b3 = f2bf(v.w * inv);
    uint2 o; o.x = b0 | (b1 << 16); o.y = b2 | (b3 << 16);
    ((uint2*)(xbf + (size_t)row * HH))[l32] = o;
    if (l32 == 0) lam[row] = expf(dw + lam_b[0]);
}

// local partials for one (tile, t-group): no cross-lane ops; base-2 exps.
__device__ __forceinline__ void tile_part(const floatx4& acc, int s0, int t,
                                          float lm2, const float4& yv,
                                          float& S, float& W, float& Y) {
    float v0 = (s0 + 0 < t) ? (acc[0] + 1.f) * 0.5f : 0.f;
    float v1 = (s0 + 1 < t) ? (acc[1] + 1.f) * 0.5f : 0.f;
    float v2 = (s0 + 2 < t) ? (acc[2] + 1.f) * 0.5f : 0.f;
    float v3 = (s0 + 3 < t) ? (acc[3] + 1.f) * 0.5f : 0.f;
    float suf3 = v3;
    float suf2 = v2 + suf3;
    float suf1 = v1 + suf2;
    float suf0 = v0 + suf1;
    float e0 = exp2f(-lm2 * suf0);
    float e1 = exp2f(-lm2 * suf1);
    float e2 = exp2f(-lm2 * suf2);
    float e3 = exp2f(-lm2 * suf3);
    float w0 = v0 * e0, w1 = v1 * e1, w2 = v2 * e2, w3 = v3 * e3;
    S = suf0;
    W = (w0 + w1) + (w2 + w3);
    Y = (w0 * yv.x + w1 * yv.y) + (w2 * yv.z + w3 * yv.w);
}

// cross-quad totals for one tile's S: tT (full tile total, per-t) and
// hq (sum of higher-quad totals, per-quad deferred decay base).
__device__ __forceinline__ void xquad(float S, int tl, int quad,
                                      float& tT, float& hq) {
    float q0 = __shfl(S, tl);
    float q1 = __shfl(S, tl + 16);
    float q2 = __shfl(S, tl + 32);
    float q3 = __shfl(S, tl + 48);
    tT = (q0 + q1) + (q2 + q3);
    hq = (quad < 1 ? q1 : 0.f) + (quad < 2 ? q2 : 0.f) +
         (quad < 3 ? q3 : 0.f);
}

// Kernel B: one block per (b, u = 32-t supertile). 4 waves split the s-range
// (wave 3 = highest s); t-pairing (one A-tile load feeds 8 MFMAs); sub-batch
// of 2 s-tiles with hoisted loads. Resolution defers the cross-iteration
// decay to ONE factor exp2(-lam2*run) per sub-batch, so the loop-carried
// chain is a single add (run += tT).
__global__ __launch_bounds__(256, 4)
void sim_fused(const unsigned short* __restrict__ xbf,
               const float* __restrict__ lam,
               const float* __restrict__ y,
               float* __restrict__ out) {
    const int b    = blockIdx.x & 31;
    const int u    = 31 - (blockIdx.x >> 5);     // largest supertiles first
    const int tid  = threadIdx.x;
    const int w    = tid >> 6;
    const int lane = tid & 63;
    const int tl   = lane & 15;
    const int quad = lane >> 4;

    const size_t rowbase = (size_t)b * TT;
    const int t0 = u * 32 + tl;
    const int t1 = t0 + 16;
    const float lam2_0 = lam[rowbase + t0] * LOG2E;
    const float lam2_1 = lam[rowbase + t1] * LOG2E;
    const float* yb = y + rowbase;

    __shared__ float Wc[4][2][16], Yc[4][2][16], Tc[4][2][16];

    // preload both B-fragment sets (t-tile 2u and 2u+1)
    short8 bq0[4], bq1[4];
    const short8* q0r = (const short8*)(xbf + (rowbase + t0) * HH);
    const short8* q1r = (const short8*)(xbf + (rowbase + t1) * HH);
    #pragma unroll
    for (int kk = 0; kk < 4; kk++) {
        bq0[kk] = q0r[kk * 4 + quad];
        bq1[kk] = q1r[kk * 4 + quad];
    }

    // wave's contiguous range of 16-wide s-tiles
    const int nst = 2 * u + 2;
    const int qn = nst >> 2, rem = nst & 3;
    const int cnt   = qn + (w < rem ? 1 : 0);
    const int start = w * qn + (w < rem ? w : rem);

    float wl0 = 0.f, yl0 = 0.f, run0 = 0.f;
    float wl1 = 0.f, yl1 = 0.f, run1 = 0.f;

    const int nsb = (cnt + 1) >> 1;
    for (int sb = nsb - 1; sb >= 0; --sb) {
        const int jA = start + 2 * sb;          // lower s-tile
        const bool vB = (2 * sb + 1) < cnt;     // higher s-tile valid?
        const int sbaseA = jA << 4;
        const int sbaseB = vB ? ((jA + 1) << 4) : sbaseA;

        // ---- hoist ALL loads for the sub-batch ----
        const short8* arA = (const short8*)(xbf + (rowbase + sbaseA + tl) * HH);
        const short8* arB = (const short8*)(xbf + (rowbase + sbaseB + tl) * HH);
        short8 afA[4], afB[4];
        #pragma unroll
        for (int kk = 0; kk < 4; kk++) {
            afA[kk] = arA[kk * 4 + quad];
            afB[kk] = arB[kk * 4 + quad];
        }
        float4 yvA = ((const float4*)(yb + sbaseA))[quad];
        float4 yvB = ((const float4*)(yb + sbaseB))[quad];

        // ---- 16 MFMAs, 4 independent acc chains ----
        floatx4 aA0 = {0,0,0,0}, aA1 = {0,0,0,0};
        floatx4 aB0 = {0,0,0,0}, aB1 = {0,0,0,0};
        #pragma unroll
        for (int kk = 0; kk < 4; kk++) {
            aA0 = __builtin_amdgcn_mfma_f32_16x16x32_bf16(afA[kk], bq0[kk], aA0, 0, 0, 0);
            aA1 = __builtin_amdgcn_mfma_f32_16x16x32_bf16(afA[kk], bq1[kk], aA1, 0, 0, 0);
            aB0 = __builtin_amdgcn_mfma_f32_16x16x32_bf16(afB[kk], bq0[kk], aB0, 0, 0, 0);
            aB1 = __builtin_amdgcn_mfma_f32_16x16x32_bf16(afB[kk], bq1[kk], aB1, 0, 0, 0);
        }

        const int s0A = sbaseA + quad * 4;
        const int s0B = vB ? (sbaseB + quad * 4) : 0x40000000;  // masks all

        // ---- local partials (no cross-lane) ----
        float SB0, WB0, YB0, SB1, WB1, YB1;
        float SA0, WA0, YA0, SA1, WA1, YA1;
        tile_part(aB0, s0B, t0, lam2_0, yvB, SB0, WB0, YB0);
        tile_part(aB1, s0B, t1, lam2_1, yvB, SB1, WB1, YB1);
        tile_part(aA0, s0A, t0, lam2_0, yvA, SA0, WA0, YA0);
        tile_part(aA1, s0A, t1, lam2_1, yvA, SA1, WA1, YA1);

        // ---- cross-quad totals (independent of run) ----
        float tTB0, hqB0, tTA0, hqA0, tTB1, hqB1, tTA1, hqA1;
        xquad(SB0, tl, quad, tTB0, hqB0);
        xquad(SB1, tl, quad, tTB1, hqB1);
        xquad(SA0, tl, quad, tTA0, hqA0);
        xquad(SA1, tl, quad, tTA1, hqA1);

        // ---- local scales (independent of run) + one run factor ----
        float scB0 = exp2f(-lam2_0 * hqB0);
        float scA0 = exp2f(-lam2_0 * (hqA0 + tTB0));
        float scB1 = exp2f(-lam2_1 * hqB1);
        float scA1 = exp2f(-lam2_1 * (hqA1 + tTB1));
        float er0 = exp2f(-lam2_0 * run0);
        float er1 = exp2f(-lam2_1 * run1);
        wl0 += er0 * (WB0 * scB0 + WA0 * scA0);
        yl0 += er0 * (YB0 * scB0 + YA0 * scA0);
        wl1 += er1 * (WB1 * scB1 + WA1 * scA1);
        yl1 += er1 * (YB1 * scB1 + YA1 * scA1);
        run0 += tTB0 + tTA0;
        run1 += tTB1 + tTA1;
    }

    // ---- cross-quad final reduce, wave partials to LDS ----
    float Wt0 = __shfl(wl0, tl) + __shfl(wl0, tl + 16) +
                __shfl(wl0, tl + 32) + __shfl(wl0, tl + 48);
    float Yt0 = __shfl(yl0, tl) + __shfl(yl0, tl + 16) +
                __shfl(yl0, tl + 32) + __shfl(yl0, tl + 48);
    float Wt1 = __shfl(wl1, tl) + __shfl(wl1, tl + 16) +
                __shfl(wl1, tl + 32) + __shfl(wl1, tl + 48);
    float Yt1 = __shfl(yl1, tl) + __shfl(yl1, tl + 16) +
                __shfl(yl1, tl + 32) + __shfl(yl1, tl + 48);
    if (quad == 0) {
        Wc[w][0][tl] = Wt0; Yc[w][0][tl] = Yt0; Tc[w][0][tl] = run0;
        Wc[w][1][tl] = Wt1; Yc[w][1][tl] = Yt1; Tc[w][1][tl] = run1;
    }
    __syncthreads();

    // ---- merge 4 wave-chunks (wave 3 = highest s, no rescale) ----
    if (tid < 32) {
        const int g = tid >> 4, l = tid & 15;
        const int t = u * 32 + g * 16 + l;
        const float lt2 = lam[rowbase + t] * LOG2E;
        float A = 0.f, W = 0.f, Y = 0.f;
        #pragma unroll
        for (int ww = 3; ww >= 0; --ww) {
            float sc = exp2f(-lt2 * A);
            W += Wc[ww][g][l] * sc;
            Y += Yc[ww][g][l] * sc;
            A += Tc[ww][g][l];
        }
        float r = Y / (W + 1e-6f);
        out[rowbase + t] = fminf(fmaxf(r, 0.01f), 0.99f);
    }
}

extern "C" void kernel_launch(void* const* d_in, const int* in_sizes, int n_in,
                              void* d_out, int out_size, void* d_ws, size_t ws_size,
                              hipStream_t stream) {
    const float* y     = (const float*)d_in[0];
    const int*   seq   = (const int*)  d_in[1];
    const float* embd  = (const float*)d_in[2];
    const float* lam_w = (const float*)d_in[3];
    const float* lam_b = (const float*)d_in[4];
    float* out = (float*)d_out;

    unsigned short* xbf = (unsigned short*)d_ws;            // 8 MB
    float* lam = (float*)(xbf + (size_t)BB * TT * HH);      // 128 KB

    gather_norm<<<BB * TT / 8, 256, 0, stream>>>(seq, embd, lam_w, lam_b, xbf, lam);
    sim_fused<<<BB * 32, 256, 0, stream>>>(xbf, lam, y, out);
}